// Round 7
// baseline (443.620 us; speedup 1.0000x reference)
//
#include <hip/hip_runtime.h>

#define TT 1024
#define NB 4096
#define HH 50
#define DTC 0.1f
#define NL2E2 -2.8853900817779268f   // -2*log2(e); state is h' = NL2E2*h
#define INVS  (-0.34657359027997264f) // 1/NL2E2

typedef __attribute__((ext_vector_type(8))) short short8;
typedef __attribute__((ext_vector_type(4))) float float4v;
typedef __attribute__((ext_vector_type(4))) unsigned int uint4v;

__device__ __forceinline__ unsigned short f2bf(float f) {
    unsigned int u = __builtin_bit_cast(unsigned int, f);
    u += 0x7FFFu + ((u >> 16) & 1u);   // RNE
    return (unsigned short)(u >> 16);
}

// Logical augmented matrix (scaled by NL2E2; sigmoid-1/2 and dt folded):
//   rows 0..49:  [0.2*Jrec | 0.1*bias | 0.1*Jin | 0]
//   row  50:     [0.2*Jout@Jrec | 0.1*Jout@bias | 0.1*Jout@Jin | 0]  (out recurrence)
//   rows 51..63: 0.   B slots: 0..49 = rcp(1+exp2(h')), 50 = 1, 51 = x_t.
// Stored GATHERED per M-tile t with row map rho_t(d)=32(t>>1)+4(t&1)+8(d>>2)+(d&3):
// the 16 C-rows lane (q,n) produces are exactly its 16 B k-slots next step.
__global__ void setup_kernel(const float* __restrict__ Jin,
                             const float* __restrict__ Jrec,
                             const float* __restrict__ Jout,
                             const float* __restrict__ bias,
                             const float* __restrict__ h0,
                             float* __restrict__ out0,
                             unsigned short* __restrict__ Astore) {
    const int tid = threadIdx.x;
    const int blk = blockIdx.x;
    if (blk < 16) {
        const int col = blk * 256 + tid;
        float s = 0.f;
        for (int i = 0; i < HH; ++i) s += Jout[i] * h0[i * NB + col];
        out0[col] = s;
    } else {
        // Astore[((t*2+c)*64 + lane)*8 + j] = NL2E2 * A_logical[rho_t(m)][32c+8q+j]
        for (int idx = tid; idx < 4096; idx += 256) {
            const int j = idx & 7;
            const int lane = (idx >> 3) & 63;
            const int tc = idx >> 9;            // 0..7
            const int t = tc >> 1, c = tc & 1;
            const int q = lane >> 4, m = lane & 15;
            const int srow = 32 * (t >> 1) + 4 * (t & 1) + 8 * (m >> 2) + (m & 3);
            const int scol = 32 * c + 8 * q + j;
            float v = 0.f;
            if (srow < HH) {
                if (scol < HH)           v = 2.0f * DTC * Jrec[srow * HH + scol];
                else if (scol == HH)     v = DTC * bias[srow];
                else if (scol == HH + 1) v = DTC * Jin[srow];
            } else if (srow == HH) {
                if (scol < HH) {
                    float s = 0.f;
                    for (int i = 0; i < HH; ++i) s += Jout[i] * Jrec[i * HH + scol];
                    v = 2.0f * DTC * s;
                } else if (scol == HH) {
                    float s = 0.f;
                    for (int i = 0; i < HH; ++i) s += Jout[i] * bias[i];
                    v = DTC * s;
                } else if (scol == HH + 1) {
                    float s = 0.f;
                    for (int i = 0; i < HH; ++i) s += Jout[i] * Jin[i];
                    v = DTC * s;
                }
            }
            Astore[idx] = f2bf(NL2E2 * v);
        }
    }
}

// 256 blocks x 64 threads: one wave owns 16 columns and the FULL 64-row state.
// No LDS, no barriers. Global I/O batched per 8 steps (no in-loop vmcnt waits).
__global__ void __launch_bounds__(64) rnn_kernel(
        const float* __restrict__ x,
        const float* __restrict__ h0,
        const float* __restrict__ out0,
        const unsigned short* __restrict__ Astore,
        float* __restrict__ out) {
    const int lane = threadIdx.x;
    const int q = lane >> 4, n = lane & 15;
    const int col = (blockIdx.x << 4) + n;
    const bool sp = (q == 2);                 // lanes owning k-slots 48..51 (out=50, x=51)

    // A fragments: 4 tiles x 2 k-chunks, 16B per lane each
    short8 Af[4][2];
    const short8* Ap = (const short8*)Astore;
#pragma unroll
    for (int t = 0; t < 4; ++t)
#pragma unroll
        for (int c = 0; c < 2; ++c)
            Af[t][c] = Ap[(t * 2 + c) * 64 + lane];

    // h state (scaled): h[t][r] holds state row 32(t>>1)+4(t&1)+8q+r, column col
    float h[4][4];
    const float vo = out0[col];
#pragma unroll
    for (int t = 0; t < 4; ++t)
#pragma unroll
        for (int r = 0; r < 4; ++r) {
            const int row = 32 * (t >> 1) + 4 * (t & 1) + 8 * q + r;
            const int rc = (row < HH) ? row : 0;
            float v = h0[rc * NB + col];
            v = (row < HH) ? v : ((row == HH) ? vo : 0.f);
            h[t][r] = NL2E2 * v;
        }

    const float* xp = x + col;
    float* outp = out + col;

    unsigned int bu[4][2];
    // sigma for tile t: r' = rcp(1+exp2(h')), paired reciprocals (1 rcp / 2 vals),
    // pack to bf16 (round-half-up). Tile 2 sp lanes: slot50='1', slot51=x.
#define PACKT(t, xv)                                                          \
    {                                                                         \
        float a0 = 1.0f + __builtin_amdgcn_exp2f(h[t][0]);                    \
        float a1 = 1.0f + __builtin_amdgcn_exp2f(h[t][1]);                    \
        float a2 = 1.0f + __builtin_amdgcn_exp2f(h[t][2]);                    \
        float a3 = 1.0f + __builtin_amdgcn_exp2f(h[t][3]);                    \
        float w01 = __builtin_amdgcn_rcpf(a0 * a1);                           \
        float w23 = __builtin_amdgcn_rcpf(a2 * a3);                           \
        unsigned int u0 = __builtin_bit_cast(unsigned int, a1 * w01);         \
        unsigned int u1 = __builtin_bit_cast(unsigned int, a0 * w01);         \
        unsigned int u2 = __builtin_bit_cast(unsigned int, a3 * w23);         \
        unsigned int u3 = __builtin_bit_cast(unsigned int, a2 * w23);         \
        if ((t) == 2) {                                                       \
            u2 = sp ? 0x3F800000u : u2;                                       \
            u3 = sp ? __builtin_bit_cast(unsigned int, (xv)) : u3;            \
        }                                                                     \
        u0 += 0x8000u; u1 += 0x8000u; u2 += 0x8000u; u3 += 0x8000u;           \
        bu[t][0] = __builtin_amdgcn_perm(u1, u0, 0x07060302u);                \
        bu[t][1] = __builtin_amdgcn_perm(u3, u2, 0x07060302u);                \
    }

    // x batch for group 0 (sp lanes only)
    float xs[8], xt[8], ob[8];
#pragma unroll
    for (int i = 0; i < 8; ++i) xs[i] = sp ? xp[i * NB] : 0.f;

    // initial B(t=0)
    PACKT(0, 0.f) PACKT(1, 0.f) PACKT(2, xs[0]) PACKT(3, 0.f)

    for (int g = 0; g < TT / 8; ++g) {
        // prefetch next group's x (consumed next group -> latency fully hidden)
        const int base = (g + 1) * 8;
        if (sp) {
#pragma unroll
            for (int i = 0; i < 8; ++i) {
                const int idx = (base + i < TT) ? base + i : TT - 1;
                xt[i] = xp[idx * NB];
            }
        }

#pragma unroll
        for (int i = 0; i < 8; ++i) {
            uint4v b0u = {bu[0][0], bu[0][1], bu[1][0], bu[1][1]};
            uint4v b1u = {bu[2][0], bu[2][1], bu[3][0], bu[3][1]};
            short8 b0 = __builtin_bit_cast(short8, b0u);
            short8 b1 = __builtin_bit_cast(short8, b1u);

#pragma unroll
            for (int t2 = 0; t2 < 4; ++t2) {
                float4v c;
#pragma unroll
                for (int r = 0; r < 4; ++r) c[r] = (1.0f - DTC) * h[t2][r];
                c = __builtin_amdgcn_mfma_f32_16x16x32_bf16(Af[t2][0], b0, c, 0, 0, 0);
                c = __builtin_amdgcn_mfma_f32_16x16x32_bf16(Af[t2][1], b1, c, 0, 0, 0);
#pragma unroll
                for (int r = 0; r < 4; ++r) h[t2][r] = c[r];
            }

            ob[i] = h[2][2];   // state row 50 = scaled out_t (sp lanes)

            const float xnext = (i < 7) ? xs[i + 1] : xt[0];
            PACKT(0, 0.f) PACKT(1, 0.f) PACKT(2, xnext) PACKT(3, 0.f)
        }

        // batched out stores (fire-and-forget) + x rotate
        if (sp) {
            const int tb = g * 8;
#pragma unroll
            for (int i = 0; i < 8; ++i) outp[(tb + i) * NB] = ob[i] * INVS;
        }
#pragma unroll
        for (int i = 0; i < 8; ++i) xs[i] = xt[i];
    }
#undef PACKT
}

extern "C" void kernel_launch(void* const* d_in, const int* in_sizes, int n_in,
                              void* d_out, int out_size, void* d_ws, size_t ws_size,
                              hipStream_t stream) {
    (void)in_sizes; (void)n_in; (void)out_size; (void)ws_size;
    const float* x    = (const float*)d_in[0];
    const float* Jin  = (const float*)d_in[1];
    const float* Jrec = (const float*)d_in[2];
    const float* Jout = (const float*)d_in[3];
    const float* bias = (const float*)d_in[4];
    const float* h0   = (const float*)d_in[5];
    float* out = (float*)d_out;

    float* ws_out0 = (float*)d_ws;                            // 4096 f32
    unsigned short* ws_A = (unsigned short*)(ws_out0 + NB);   // 4096 bf16 gathered

    hipLaunchKernelGGL(setup_kernel, dim3(17), dim3(256), 0, stream,
                       Jin, Jrec, Jout, bias, h0, ws_out0, ws_A);
    hipLaunchKernelGGL(rnn_kernel, dim3(256), dim3(64), 0, stream,
                       x, h0, ws_out0, ws_A, out);
}